// Round 1
// baseline (14529.321 us; speedup 1.0000x reference)
//
#include <hip/hip_runtime.h>
#include <cmath>

#define B_ 256
#define T_ 256
#define F_ 40
#define H_ 256
#define A_ 64
#define HOR_ 60
#define DSP_ 192
#define G4_ 1024   // 4*H
#define AD_LD 772  // padded row stride of [py | context(512) | h(256)]

__device__ __forceinline__ float sigm(float x){ return 1.f/(1.f+expf(-x)); }

__device__ __forceinline__ float wred_sum(float v){
  #pragma unroll
  for (int o=32;o>0;o>>=1) v += __shfl_xor(v,o);
  return v;
}
__device__ __forceinline__ float wred_max(float v){
  #pragma unroll
  for (int o=32;o>0;o>>=1) v = fmaxf(v,__shfl_xor(v,o));
  return v;
}

// ---------- weight reorder: dst[k, 4u+r] = {Wx|Wh}[k, r*H + u] ----------
__global__ void reorder_w(const float* __restrict__ Wx, const float* __restrict__ Wh,
                          float* __restrict__ dst, int KX, int Ktot){
  int idx = blockIdx.x*256 + threadIdx.x;
  if (idx >= Ktot*G4_) return;
  int k = idx >> 10, c = idx & 1023;
  int u = c >> 2, r = c & 3;
  int sc = r*H_ + u;
  dst[idx] = (k < KX) ? Wx[(size_t)k*G4_ + sc] : Wh[(size_t)(k-KX)*G4_ + sc];
}
__global__ void reorder_bias(const float* __restrict__ src, float* __restrict__ dst){
  int i = blockIdx.x*256 + threadIdx.x;
  if (i < G4_) dst[i] = src[(i&3)*H_ + (i>>2)];
}

// ---------- generic tiled SGEMM: C = A[M,K] @ W[K,N] (+bias) (+tanh) ----------
__global__ __launch_bounds__(256) void sgemm_bias(
    const float* __restrict__ A, const float* __restrict__ W,
    const float* __restrict__ bias, float* __restrict__ C,
    int M, int N, int K, int act)
{
  __shared__ float As[64][17];
  __shared__ float Ws[16][64];
  int tid = threadIdx.x;
  int tr = tid >> 4, tc = tid & 15;
  int row0 = blockIdx.y * 64, col0 = blockIdx.x * 64;
  float acc[4][4] = {};
  for (int k0 = 0; k0 < K; k0 += 16) {
    for (int i = tid; i < 64*16; i += 256) {
      int r = i >> 4, kk = i & 15;
      int gr = row0 + r, gk = k0 + kk;
      As[r][kk] = (gr < M && gk < K) ? A[(size_t)gr*K + gk] : 0.f;
    }
    for (int i = tid; i < 16*64; i += 256) {
      int r = i >> 6, c = i & 63;
      int gk = k0 + r, gc = col0 + c;
      Ws[r][c] = (gk < K && gc < N) ? W[(size_t)gk*N + gc] : 0.f;
    }
    __syncthreads();
    #pragma unroll
    for (int kk=0;kk<16;kk++){
      float a0 = As[tr*4+0][kk], a1 = As[tr*4+1][kk];
      float a2v = As[tr*4+2][kk], a3 = As[tr*4+3][kk];
      float4 b4 = *(const float4*)&Ws[kk][tc*4];
      acc[0][0]+=a0*b4.x; acc[0][1]+=a0*b4.y; acc[0][2]+=a0*b4.z; acc[0][3]+=a0*b4.w;
      acc[1][0]+=a1*b4.x; acc[1][1]+=a1*b4.y; acc[1][2]+=a1*b4.z; acc[1][3]+=a1*b4.w;
      acc[2][0]+=a2v*b4.x; acc[2][1]+=a2v*b4.y; acc[2][2]+=a2v*b4.z; acc[2][3]+=a2v*b4.w;
      acc[3][0]+=a3*b4.x; acc[3][1]+=a3*b4.y; acc[3][2]+=a3*b4.z; acc[3][3]+=a3*b4.w;
    }
    __syncthreads();
  }
  #pragma unroll
  for (int i=0;i<4;i++){
    int r = row0 + tr*4 + i; if (r >= M) continue;
    #pragma unroll
    for (int j=0;j<4;j++){
      int c = col0 + tc*4 + j; if (c >= N) continue;
      float vv = acc[i][j] + (bias ? bias[c] : 0.f);
      if (act == 1) vv = tanhf(vv);
      C[(size_t)r*N + c] = vv;
    }
  }
}

// ---------- encoder step: gates = hsp[:,t,:] @ Wx' + h @ Wh' + b' ; cell ----------
// blockIdx.z = dir (0 fwd, 1 bwd). Weights interleaved-gate layout, Wx/Wh stacked [448,1024].
__global__ __launch_bounds__(256) void enc_step(
    const float* __restrict__ hsp, const float* __restrict__ Wf, const float* __restrict__ Wb,
    const float* __restrict__ brf, const float* __restrict__ brb,
    const float* __restrict__ h_in, float* __restrict__ h_out, float* __restrict__ cst,
    float* __restrict__ enc_out, int s)
{
  __shared__ float As[16][34];   // transposed A tile [k][row]
  __shared__ float Ws[16][64];
  int dir = blockIdx.z;
  int t = dir ? (T_-1-s) : s;
  const float* W  = dir ? Wb  : Wf;
  const float* br = dir ? brb : brf;
  const float* hin  = h_in  + dir*(B_*H_);
  float* hout = h_out + dir*(B_*H_);
  float* cbuf = cst   + dir*(B_*H_);
  int tid = threadIdx.x;
  int tr = tid >> 4, tc = tid & 15;
  int row0 = blockIdx.y * 32, col0 = blockIdx.x * 64;
  float acc[2][4] = {};
  for (int k0 = 0; k0 < DSP_+H_; k0 += 16) {
    #pragma unroll
    for (int i = 0; i < 2; i++) {
      int idx = tid + i*256;
      int r = idx >> 4, kk = idx & 15;
      int b = row0 + r, k = k0 + kk;
      float vv = (k < DSP_) ? hsp[((size_t)b*T_ + t)*DSP_ + k]
                            : hin[b*H_ + (k-DSP_)];
      As[kk][r] = vv;
    }
    #pragma unroll
    for (int i = 0; i < 4; i++) {
      int idx = tid + i*256;
      int r = idx >> 6, c = idx & 63;
      Ws[r][c] = W[(size_t)(k0+r)*G4_ + col0 + c];
    }
    __syncthreads();
    #pragma unroll
    for (int kk=0;kk<16;kk++){
      float2 a2 = *(const float2*)&As[kk][tr*2];
      float4 b4 = *(const float4*)&Ws[kk][tc*4];
      acc[0][0]+=a2.x*b4.x; acc[0][1]+=a2.x*b4.y; acc[0][2]+=a2.x*b4.z; acc[0][3]+=a2.x*b4.w;
      acc[1][0]+=a2.y*b4.x; acc[1][1]+=a2.y*b4.y; acc[1][2]+=a2.y*b4.z; acc[1][3]+=a2.y*b4.w;
    }
    __syncthreads();
  }
  int U = (col0 >> 2) + tc;                 // hidden unit
  float bi = br[col0 + tc*4 + 0];
  float bf = br[col0 + tc*4 + 1];
  float bg = br[col0 + tc*4 + 2];
  float bon = br[col0 + tc*4 + 3];
  #pragma unroll
  for (int i=0;i<2;i++){
    int b = row0 + tr*2 + i;
    float gi = acc[i][0]+bi, gf = acc[i][1]+bf, gg = acc[i][2]+bg, go = acc[i][3]+bon;
    float cold = cbuf[b*H_ + U];
    float cn = sigm(gf)*cold + sigm(gi)*tanhf(gg);
    float hn = sigm(go)*tanhf(cn);
    cbuf[b*H_+U] = cn;
    hout[b*H_+U] = hn;
    enc_out[((size_t)b*T_ + t)*(2*H_) + dir*H_ + U] = hn;
  }
}

// ---------- decoder LSTM step: A row = [py | context | h] (769), W stacked [769,1024] ----------
__global__ __launch_bounds__(256) void dec_step(
    const float* __restrict__ Ad, const float* __restrict__ Wc, const float* __restrict__ brd,
    float* __restrict__ c_dec, float* __restrict__ h_dec)
{
  __shared__ float As[16][34];
  __shared__ float Ws[16][64];
  const int K = 769;
  int tid = threadIdx.x;
  int tr = tid >> 4, tc = tid & 15;
  int row0 = blockIdx.y * 32, col0 = blockIdx.x * 64;
  float acc[2][4] = {};
  for (int k0 = 0; k0 < K; k0 += 16) {
    #pragma unroll
    for (int i = 0; i < 2; i++) {
      int idx = tid + i*256;
      int r = idx >> 4, kk = idx & 15;
      int b = row0 + r, k = k0 + kk;
      As[kk][r] = (k < K) ? Ad[(size_t)b*AD_LD + k] : 0.f;
    }
    #pragma unroll
    for (int i = 0; i < 4; i++) {
      int idx = tid + i*256;
      int r = idx >> 6, c = idx & 63;
      int k = k0 + r;
      Ws[r][c] = (k < K) ? Wc[(size_t)k*G4_ + col0 + c] : 0.f;
    }
    __syncthreads();
    #pragma unroll
    for (int kk=0;kk<16;kk++){
      float2 a2 = *(const float2*)&As[kk][tr*2];
      float4 b4 = *(const float4*)&Ws[kk][tc*4];
      acc[0][0]+=a2.x*b4.x; acc[0][1]+=a2.x*b4.y; acc[0][2]+=a2.x*b4.z; acc[0][3]+=a2.x*b4.w;
      acc[1][0]+=a2.y*b4.x; acc[1][1]+=a2.y*b4.y; acc[1][2]+=a2.y*b4.z; acc[1][3]+=a2.y*b4.w;
    }
    __syncthreads();
  }
  int U = (col0 >> 2) + tc;
  float bi = brd[col0 + tc*4 + 0];
  float bf = brd[col0 + tc*4 + 1];
  float bg = brd[col0 + tc*4 + 2];
  float bon = brd[col0 + tc*4 + 3];
  #pragma unroll
  for (int i=0;i<2;i++){
    int b = row0 + tr*2 + i;
    float gi = acc[i][0]+bi, gf = acc[i][1]+bf, gg = acc[i][2]+bg, go = acc[i][3]+bon;
    float cold = c_dec[b*H_ + U];
    float cn = sigm(gf)*cold + sigm(gi)*tanhf(gg);
    float hn = sigm(go)*tanhf(cn);
    c_dec[b*H_+U] = cn;
    h_dec[b*H_+U] = hn;
  }
}

// ---------- attention (one block per batch row) ----------
// copies h into A_dec, emits y_{s-1} (fused head), computes context into A_dec
__global__ __launch_bounds__(256) void attn_step(
    const float* __restrict__ enc_out, const float* __restrict__ enc_proj,
    const float* __restrict__ Wd, const float* __restrict__ v,
    const float* __restrict__ Wo, const float* __restrict__ bo,
    const float* __restrict__ h_dec, float* __restrict__ Ad,
    float* __restrict__ out, int s)
{
  __shared__ float sh_h[256], sh_hwd[64], sh_v[64], sh_sc[256], sh_w[256];
  __shared__ float sh_red[4], sh_red2[4];
  int b = blockIdx.x, tid = threadIdx.x;
  float hv = h_dec[b*H_ + tid];
  sh_h[tid] = hv;
  Ad[(size_t)b*AD_LD + 513 + tid] = hv;
  if (tid < 64) sh_v[tid] = v[tid];
  __syncthreads();
  if (s > 0) {          // y_{s-1} = h_s @ Wo + bo  (uniform branch per block)
    float p = hv * Wo[tid];
    p = wred_sum(p);
    if ((tid & 63) == 0) sh_red[tid>>6] = p;
    __syncthreads();
    if (tid == 0) {
      float y = sh_red[0]+sh_red[1]+sh_red[2]+sh_red[3] + bo[0];
      out[b*HOR_ + (s-1)] = y;
      Ad[(size_t)b*AD_LD] = y;       // py for this step's LSTM
    }
    __syncthreads();
  }
  if (tid < 64) {       // hWd
    float a = 0.f;
    for (int j=0;j<H_;j++) a += sh_h[j]*Wd[j*A_ + tid];
    sh_hwd[tid] = a;
  }
  __syncthreads();
  int aa = tid & 3;     // scores: 4 lanes per t, coalesced float4 reads
  #pragma unroll
  for (int p=0;p<4;p++){
    int t = p*64 + (tid>>2);
    const float4* ep4 = (const float4*)(enc_proj + ((size_t)(b*T_+t))*A_ + aa*16);
    float partial = 0.f;
    #pragma unroll
    for (int q=0;q<4;q++){
      float4 e4 = ep4[q];
      int a0 = aa*16 + q*4;
      partial += tanhf(e4.x + sh_hwd[a0+0]) * sh_v[a0+0];
      partial += tanhf(e4.y + sh_hwd[a0+1]) * sh_v[a0+1];
      partial += tanhf(e4.z + sh_hwd[a0+2]) * sh_v[a0+2];
      partial += tanhf(e4.w + sh_hwd[a0+3]) * sh_v[a0+3];
    }
    partial += __shfl_xor(partial, 1);
    partial += __shfl_xor(partial, 2);
    if (aa == 0) sh_sc[t] = partial;
  }
  __syncthreads();
  float sc = sh_sc[tid];               // softmax over T in LDS
  float m = wred_max(sc);
  if ((tid&63)==0) sh_red[tid>>6] = m;
  __syncthreads();
  m = fmaxf(fmaxf(sh_red[0],sh_red[1]), fmaxf(sh_red[2],sh_red[3]));
  float e = expf(sc - m);
  float su = wred_sum(e);
  if ((tid&63)==0) sh_red2[tid>>6] = su;
  __syncthreads();
  su = (sh_red2[0]+sh_red2[1])+(sh_red2[2]+sh_red2[3]);
  sh_w[tid] = e / su;
  __syncthreads();
  float acc0=0.f, acc1=0.f;            // context
  const float* eo = enc_out + (size_t)b*T_*(2*H_);
  for (int t=0;t<T_;t++){
    float w = sh_w[t];
    acc0 += w * eo[t*512 + tid];
    acc1 += w * eo[t*512 + 256 + tid];
  }
  Ad[(size_t)b*AD_LD + 1 + tid]   = acc0;
  Ad[(size_t)b*AD_LD + 257 + tid] = acc1;
}

__global__ __launch_bounds__(256) void final_y(const float* __restrict__ h_dec,
    const float* __restrict__ Wo, const float* __restrict__ bo, float* __restrict__ out){
  __shared__ float sh[4];
  int b = blockIdx.x, tid = threadIdx.x;
  float p = h_dec[b*H_+tid]*Wo[tid];
  p = wred_sum(p);
  if ((tid&63)==0) sh[tid>>6]=p;
  __syncthreads();
  if (tid==0) out[b*HOR_ + HOR_-1] = sh[0]+sh[1]+sh[2]+sh[3] + bo[0];
}

__global__ __launch_bounds__(256) void enc_mean_k(const float* __restrict__ enc_out,
                                                  float* __restrict__ em){
  int b = blockIdx.x, tid = threadIdx.x;
  const float* eo = enc_out + (size_t)b*T_*512;
  float s0=0.f, s1=0.f;
  for (int t=0;t<T_;t++){ s0 += eo[t*512+tid]; s1 += eo[t*512+256+tid]; }
  em[(size_t)b*512 + tid]       = s0*(1.f/T_);
  em[(size_t)b*512 + 256 + tid] = s1*(1.f/T_);
}

__global__ void py_init(const float* __restrict__ x, float* __restrict__ Ad){
  int b = blockIdx.x*256 + threadIdx.x;
  if (b < B_)
    Ad[(size_t)b*AD_LD] = (x[(size_t)b*T_*F_ + 255*F_ + 0] +
                           x[(size_t)b*T_*F_ + 255*F_ + 2]) * 0.5f;
}

extern "C" void kernel_launch(void* const* d_in, const int* in_sizes, int n_in,
                              void* d_out, int out_size, void* d_ws, size_t ws_size,
                              hipStream_t stream)
{
  const float* x    = (const float*)d_in[0];
  const float* W_sp = (const float*)d_in[1];
  const float* b_sp = (const float*)d_in[2];
  const float* Wx_ef= (const float*)d_in[3];
  const float* Wh_ef= (const float*)d_in[4];
  const float* b_ef = (const float*)d_in[5];
  const float* Wx_eb= (const float*)d_in[6];
  const float* Wh_eb= (const float*)d_in[7];
  const float* b_eb = (const float*)d_in[8];
  const float* We   = (const float*)d_in[9];
  const float* Wd   = (const float*)d_in[10];
  const float* v    = (const float*)d_in[11];
  const float* Wx_d = (const float*)d_in[12];
  const float* Wh_d = (const float*)d_in[13];
  const float* b_d  = (const float*)d_in[14];
  const float* W_ih = (const float*)d_in[15];
  const float* b_ih = (const float*)d_in[16];
  const float* W_ic = (const float*)d_in[17];
  const float* b_ic = (const float*)d_in[18];
  const float* Wo   = (const float*)d_in[19];
  const float* bo   = (const float*)d_in[20];
  float* out = (float*)d_out;
  float* ws  = (float*)d_ws;

  // workspace layout (floats)
  float* Wf   = ws;                       // 448*1024
  float* Wb   = Wf  + 458752;             // 448*1024
  float* Wdc  = Wb  + 458752;             // 769*1024
  float* brf  = Wdc + 787456;             // 1024
  float* brb  = brf + 1024;
  float* brd  = brb + 1024;
  float* hsp  = brd + 1024;               // 65536*192
  float* eo   = hsp + 12582912;           // 65536*512
  float* ep   = eo  + 33554432;           // 65536*64
  float* est  = ep  + 4194304;            // 6*65536 (h parity0[2dir], h parity1[2dir], c[2dir])
  float* em   = est + 393216;             // 256*512
  float* Ad   = em  + 131072;             // 256*772
  float* cd   = Ad  + 197632;             // 256*256
  float* hd   = cd  + 65536;              // 256*256
  size_t needed = (size_t)(hd + 65536 - ws) * sizeof(float);
  if (ws_size < needed) return;           // refuse to corrupt memory

  // weight/bias reorder to gate-interleaved layout
  reorder_w<<<dim3(1792),256,0,stream>>>(Wx_ef, Wh_ef, Wf, DSP_, 448);
  reorder_w<<<dim3(1792),256,0,stream>>>(Wx_eb, Wh_eb, Wb, DSP_, 448);
  reorder_w<<<dim3(3076),256,0,stream>>>(Wx_d,  Wh_d,  Wdc, 513, 769);
  reorder_bias<<<dim3(4),256,0,stream>>>(b_ef, brf);
  reorder_bias<<<dim3(4),256,0,stream>>>(b_eb, brb);
  reorder_bias<<<dim3(4),256,0,stream>>>(b_d,  brd);

  hipMemsetAsync(est, 0, 393216*sizeof(float), stream);

  // spatial projection: [B*T,40] @ [40,192] + b
  sgemm_bias<<<dim3(3,1024),256,0,stream>>>(x, W_sp, b_sp, hsp, B_*T_, DSP_, F_, 0);

  // bidirectional encoder scan (256 steps, both dirs per launch)
  for (int s=0;s<T_;s++){
    const float* hin = est + (s&1)*131072;
    float* hout      = est + ((s&1)^1)*131072;
    float* cst       = est + 262144;
    enc_step<<<dim3(16,8,2),256,0,stream>>>(hsp, Wf, Wb, brf, brb, hin, hout, cst, eo, s);
  }

  enc_mean_k<<<dim3(256),256,0,stream>>>(eo, em);
  sgemm_bias<<<dim3(4,4),256,0,stream>>>(em, W_ih, b_ih, hd, B_, H_, 2*H_, 1);  // dec_h (tanh)
  sgemm_bias<<<dim3(4,4),256,0,stream>>>(em, W_ic, b_ic, cd, B_, H_, 2*H_, 1);  // dec_c (tanh)
  sgemm_bias<<<dim3(1,1024),256,0,stream>>>(eo, We, nullptr, ep, B_*T_, A_, 2*H_, 0); // enc_proj
  py_init<<<dim3(1),256,0,stream>>>(x, Ad);

  // decoder: 60 steps of (attention+fused-head, LSTM-cell)
  for (int s=0;s<HOR_;s++){
    attn_step<<<dim3(256),256,0,stream>>>(eo, ep, Wd, v, Wo, bo, hd, Ad, out, s);
    dec_step<<<dim3(16,8),256,0,stream>>>(Ad, Wdc, brd, cd, hd);
  }
  final_y<<<dim3(256),256,0,stream>>>(hd, Wo, bo, out);
}